// Round 4
// baseline (65.777 us; speedup 1.0000x reference)
//
#include <hip/hip_runtime.h>
#include <math.h>

#define NE 32            // experts
#define DIM 1024         // input dim == output dim
#define NB 8192          // batch
#define F4ROW 256        // float4 per row of DIM

// ---------------------------------------------------------------------------
// Kernel 1: wsum[r] = sum_o W[r, o]   (r = e*DIM + i, rows of 1024 floats)
// 4 rows per wave, all 16 float4 loads issued before the reduces (ILP).
// 32768 rows / 16 rows-per-block = 2048 blocks.
// ---------------------------------------------------------------------------
__global__ __launch_bounds__(256) void wsum_kernel(const float* __restrict__ W,
                                                   float* __restrict__ wsum) {
    const int lane = threadIdx.x & 63;
    const int wid  = (blockIdx.x * blockDim.x + threadIdx.x) >> 6;
    const int r0   = wid * 4;

    const float4* W4 = (const float4*)W;
    float4 v[4][4];
#pragma unroll
    for (int rr = 0; rr < 4; ++rr)
#pragma unroll
        for (int j = 0; j < 4; ++j)
            v[rr][j] = W4[(size_t)(r0 + rr) * F4ROW + lane + 64 * j];

    float s[4];
#pragma unroll
    for (int rr = 0; rr < 4; ++rr) {
        const float4 a = v[rr][0], b = v[rr][1], c = v[rr][2], d = v[rr][3];
        s[rr] = ((a.x + a.y) + (a.z + a.w)) + ((b.x + b.y) + (b.z + b.w)) +
                ((c.x + c.y) + (c.z + c.w)) + ((d.x + d.y) + (d.z + d.w));
    }
#pragma unroll
    for (int off = 32; off >= 1; off >>= 1) {
        s[0] += __shfl_xor(s[0], off, 64);
        s[1] += __shfl_xor(s[1], off, 64);
        s[2] += __shfl_xor(s[2], off, 64);
        s[3] += __shfl_xor(s[3], off, 64);
    }
    if (lane == 0) {
        wsum[r0 + 0] = s[0];
        wsum[r0 + 1] = s[1];
        wsum[r0 + 2] = s[2];
        wsum[r0 + 3] = s[3];
    }
}

// ---------------------------------------------------------------------------
// Kernel 2: fused gating + combine.  2 tokens per wave, 4 waves/block.
// x rows live in registers for the whole kernel (read once from HBM).
// Gating: per expert, 64-lane dot via xor-butterfly; lane e keeps expert e's
// logit. Softmax + top2 wave-parallel over lanes 0..31 (no LDS, no barriers).
// ---------------------------------------------------------------------------
#define DOT4(acc, xv, gv)                                                      \
    acc = fmaf((xv).x, (gv).x, acc); acc = fmaf((xv).y, (gv).y, acc);          \
    acc = fmaf((xv).z, (gv).z, acc); acc = fmaf((xv).w, (gv).w, acc);

__global__ __launch_bounds__(256) void gate_combine_kernel(
    const float* __restrict__ x,     // [B, I]
    const float* __restrict__ gw,    // [E, I]
    const float* __restrict__ gb,    // [E]
    const float* __restrict__ wsum,  // [E, I]  (from kernel 1)
    const float* __restrict__ bias,  // [E, I]
    float* __restrict__ out)         // [B, I]
{
    const int lane = threadIdx.x & 63;
    const int wave = threadIdx.x >> 6;
    const int wid  = blockIdx.x * 4 + wave;   // 0..4095
    const int t0   = wid * 2;                 // this wave's two tokens

    // x rows -> registers (the only HBM read of x)
    const float4* x4 = (const float4*)x;
    float4 xq0[4], xq1[4];
#pragma unroll
    for (int j = 0; j < 4; ++j) {
        xq0[j] = x4[(size_t)(t0 + 0) * F4ROW + lane + 64 * j];
        xq1[j] = x4[(size_t)(t0 + 1) * F4ROW + lane + 64 * j];
    }

    // gating dots: after the loop, lane e (e<32) holds logits of expert e
    float ml0 = 0.f, ml1 = 0.f;
    const float4* gw4 = (const float4*)gw;
#pragma unroll 4
    for (int e = 0; e < NE; ++e) {
        const float4 g0 = gw4[(size_t)e * F4ROW + lane];
        const float4 g1 = gw4[(size_t)e * F4ROW + lane + 64];
        const float4 g2 = gw4[(size_t)e * F4ROW + lane + 128];
        const float4 g3 = gw4[(size_t)e * F4ROW + lane + 192];

        float a0 = 0.f, a1 = 0.f;
        DOT4(a0, xq0[0], g0); DOT4(a0, xq0[1], g1);
        DOT4(a0, xq0[2], g2); DOT4(a0, xq0[3], g3);
        DOT4(a1, xq1[0], g0); DOT4(a1, xq1[1], g1);
        DOT4(a1, xq1[2], g2); DOT4(a1, xq1[3], g3);
#pragma unroll
        for (int off = 32; off >= 1; off >>= 1) {
            a0 += __shfl_xor(a0, off, 64);
            a1 += __shfl_xor(a1, off, 64);
        }
        if (lane == e) { ml0 = a0; ml1 = a1; }
    }
    const float gbl = gb[lane & 31];
    ml0 += gbl;
    ml1 += gbl;

    // wave-parallel softmax + top2 over lanes 0..31 (upper half is garbage,
    // results broadcast from lane 0 afterwards). Tie-break: lowest index.
    auto top2 = [&](float ml, float& ov0, float& ov1, int& oe0, int& oe1) {
        float m = ml;
#pragma unroll
        for (int off = 16; off >= 1; off >>= 1)
            m = fmaxf(m, __shfl_xor(m, off, 64));
        float den = expf(ml - m);
#pragma unroll
        for (int off = 16; off >= 1; off >>= 1)
            den += __shfl_xor(den, off, 64);
        // argmax 1
        float v = ml; int ix = lane;
#pragma unroll
        for (int off = 16; off >= 1; off >>= 1) {
            const float ovv = __shfl_xor(v, off, 64);
            const int   oii = __shfl_xor(ix, off, 64);
            if (ovv > v || (ovv == v && oii < ix)) { v = ovv; ix = oii; }
        }
        const int e0 = ix; const float l0 = v;   // uniform in lanes 0..31
        // argmax 2 (exclude e0)
        float v2 = (lane == e0) ? -INFINITY : ml; int ix2 = lane;
#pragma unroll
        for (int off = 16; off >= 1; off >>= 1) {
            const float ovv = __shfl_xor(v2, off, 64);
            const int   oii = __shfl_xor(ix2, off, 64);
            if (ovv > v2 || (ovv == v2 && oii < ix2)) { v2 = ovv; ix2 = oii; }
        }
        const float inv = 1.0f / den;
        ov0 = expf(l0 - m) * inv;
        ov1 = expf(v2 - m) * inv;
        oe0 = e0; oe1 = ix2;
    };

    float av0, av1; int ae0, ae1;
    top2(ml0, av0, av1, ae0, ae1);
    av0 = __shfl(av0, 0, 64); av1 = __shfl(av1, 0, 64);
    ae0 = __shfl(ae0, 0, 64); ae1 = __shfl(ae1, 0, 64);

    float bv0, bv1; int be0, be1;
    top2(ml1, bv0, bv1, be0, be1);
    bv0 = __shfl(bv0, 0, 64); bv1 = __shfl(bv1, 0, 64);
    be0 = __shfl(be0, 0, 64); be1 = __shfl(be1, 0, 64);

    // combine: out = v0*(x*ws[e0] + bias[e0]) + v1*(x*ws[e1] + bias[e1])
    float4* o4 = (float4*)out;
    {
        const float4* w0 = (const float4*)(wsum + (size_t)ae0 * DIM);
        const float4* w1 = (const float4*)(wsum + (size_t)ae1 * DIM);
        const float4* c0 = (const float4*)(bias + (size_t)ae0 * DIM);
        const float4* c1 = (const float4*)(bias + (size_t)ae1 * DIM);
#pragma unroll
        for (int j = 0; j < 4; ++j) {
            const int idx = lane + 64 * j;
            const float4 xv = xq0[j];
            const float4 A0 = w0[idx], A1 = w1[idx];
            const float4 C0 = c0[idx], C1 = c1[idx];
            float4 o;
            o.x = fmaf(av0, fmaf(xv.x, A0.x, C0.x), av1 * fmaf(xv.x, A1.x, C1.x));
            o.y = fmaf(av0, fmaf(xv.y, A0.y, C0.y), av1 * fmaf(xv.y, A1.y, C1.y));
            o.z = fmaf(av0, fmaf(xv.z, A0.z, C0.z), av1 * fmaf(xv.z, A1.z, C1.z));
            o.w = fmaf(av0, fmaf(xv.w, A0.w, C0.w), av1 * fmaf(xv.w, A1.w, C1.w));
            o4[(size_t)(t0 + 0) * F4ROW + idx] = o;
        }
    }
    {
        const float4* w0 = (const float4*)(wsum + (size_t)be0 * DIM);
        const float4* w1 = (const float4*)(wsum + (size_t)be1 * DIM);
        const float4* c0 = (const float4*)(bias + (size_t)be0 * DIM);
        const float4* c1 = (const float4*)(bias + (size_t)be1 * DIM);
#pragma unroll
        for (int j = 0; j < 4; ++j) {
            const int idx = lane + 64 * j;
            const float4 xv = xq1[j];
            const float4 A0 = w0[idx], A1 = w1[idx];
            const float4 C0 = c0[idx], C1 = c1[idx];
            float4 o;
            o.x = fmaf(bv0, fmaf(xv.x, A0.x, C0.x), bv1 * fmaf(xv.x, A1.x, C1.x));
            o.y = fmaf(bv0, fmaf(xv.y, A0.y, C0.y), bv1 * fmaf(xv.y, A1.y, C1.y));
            o.z = fmaf(bv0, fmaf(xv.z, A0.z, C0.z), bv1 * fmaf(xv.z, A1.z, C1.z));
            o.w = fmaf(bv0, fmaf(xv.w, A0.w, C0.w), bv1 * fmaf(xv.w, A1.w, C1.w));
            o4[(size_t)(t0 + 1) * F4ROW + idx] = o;
        }
    }
}

// ---------------------------------------------------------------------------
extern "C" void kernel_launch(void* const* d_in, const int* in_sizes, int n_in,
                              void* d_out, int out_size, void* d_ws, size_t ws_size,
                              hipStream_t stream) {
    const float* x    = (const float*)d_in[0];   // [B, I]
    const float* W    = (const float*)d_in[1];   // [E, I, O]
    const float* bias = (const float*)d_in[2];   // [E, O]
    const float* gw   = (const float*)d_in[3];   // [E, I]
    const float* gb   = (const float*)d_in[4];   // [E]
    // d_in[5] = topk (always 2, hardcoded)

    float* wsum = (float*)d_ws;                  // 128 KiB scratch
    float* out  = (float*)d_out;

    // K1: 32768 rows, 16 rows/block (4 waves x 4 rows) -> 2048 blocks
    wsum_kernel<<<2048, 256, 0, stream>>>(W, wsum);

    // K2: 8192 tokens, 2 per wave, 8 per block -> 1024 blocks
    gate_combine_kernel<<<1024, 256, 0, stream>>>(x, gw, gb, wsum, bias, out);
}

// Round 5
// 64.320 us; speedup vs baseline: 1.0227x; 1.0227x over previous
//
#include <hip/hip_runtime.h>
#include <math.h>

#define NE 32            // experts
#define DIM 1024         // input dim == output dim
#define NB 8192          // batch
#define F4ROW 256        // float4 per row of DIM

#define GATE_BLOCKS 512                    // 16 tokens/block (4 waves x 4)
#define WSUM_BLOCKS 2048                   // 16 rows/block (4 waves x 4 rows)

// ---------------------------------------------------------------------------
// Kernel 1: fused  (a) gating -> packed top2 per token [blocks 0..GATE_BLOCKS)
//                  (b) wsum[r] = sum_o W[r,o]           [blocks GATE_BLOCKS..)
// Gating blocks dispatch first so their compute + gw L2 traffic hides under
// the 134 MB W stream (measured round 2: this overlap is ~free).
// ---------------------------------------------------------------------------
__global__ __launch_bounds__(256) void stage1_kernel(
    const float* __restrict__ W,     // [E, I, O]
    const float* __restrict__ x,     // [B, I]
    const float* __restrict__ gw,    // [E, I]
    const float* __restrict__ gb,    // [E]
    float* __restrict__ wsum,        // [E*I]      ws
    float4* __restrict__ topinfo)    // [B] {v0,v1,e0,e1}  ws
{
    const int wave = threadIdx.x >> 6;
    const int lane = threadIdx.x & 63;

    if (blockIdx.x >= GATE_BLOCKS) {
        // ---- wsum: 4 rows per wave, all 16 loads in flight before reduce ----
        const int r0 = ((blockIdx.x - GATE_BLOCKS) * 4 + wave) * 4;
        const float4* W4 = (const float4*)W;
        float4 v[4][4];
#pragma unroll
        for (int rr = 0; rr < 4; ++rr)
#pragma unroll
            for (int j = 0; j < 4; ++j)
                v[rr][j] = W4[(size_t)(r0 + rr) * F4ROW + lane + 64 * j];

        float s[4];
#pragma unroll
        for (int rr = 0; rr < 4; ++rr) {
            const float4 a = v[rr][0], b = v[rr][1], c = v[rr][2], d = v[rr][3];
            s[rr] = ((a.x + a.y) + (a.z + a.w)) + ((b.x + b.y) + (b.z + b.w)) +
                    ((c.x + c.y) + (c.z + c.w)) + ((d.x + d.y) + (d.z + d.w));
        }
#pragma unroll
        for (int off = 32; off >= 1; off >>= 1) {
            s[0] += __shfl_xor(s[0], off, 64);
            s[1] += __shfl_xor(s[1], off, 64);
            s[2] += __shfl_xor(s[2], off, 64);
            s[3] += __shfl_xor(s[3], off, 64);
        }
        if (lane == 0) {
            wsum[r0 + 0] = s[0];
            wsum[r0 + 1] = s[1];
            wsum[r0 + 2] = s[2];
            wsum[r0 + 3] = s[3];
        }
        return;
    }

    // ---- gating: 4 tokens per wave, x rows held in registers ----
    __shared__ float logits[16][NE];
    const int tbase = blockIdx.x * 16 + wave * 4;

    const float4* x4 = (const float4*)x;
    float4 xq[4][4];
#pragma unroll
    for (int tk = 0; tk < 4; ++tk)
#pragma unroll
        for (int j = 0; j < 4; ++j)
            xq[tk][j] = x4[(size_t)(tbase + tk) * F4ROW + lane + 64 * j];

    const float4* gw4 = (const float4*)gw;
#pragma unroll 4
    for (int e = 0; e < NE; ++e) {
        const float4 g0 = gw4[(size_t)e * F4ROW + lane];
        const float4 g1 = gw4[(size_t)e * F4ROW + lane + 64];
        const float4 g2 = gw4[(size_t)e * F4ROW + lane + 128];
        const float4 g3 = gw4[(size_t)e * F4ROW + lane + 192];

        float acc[4];
#pragma unroll
        for (int tk = 0; tk < 4; ++tk) {
            float a = 0.f;
            a = fmaf(xq[tk][0].x, g0.x, a); a = fmaf(xq[tk][0].y, g0.y, a);
            a = fmaf(xq[tk][0].z, g0.z, a); a = fmaf(xq[tk][0].w, g0.w, a);
            a = fmaf(xq[tk][1].x, g1.x, a); a = fmaf(xq[tk][1].y, g1.y, a);
            a = fmaf(xq[tk][1].z, g1.z, a); a = fmaf(xq[tk][1].w, g1.w, a);
            a = fmaf(xq[tk][2].x, g2.x, a); a = fmaf(xq[tk][2].y, g2.y, a);
            a = fmaf(xq[tk][2].z, g2.z, a); a = fmaf(xq[tk][2].w, g2.w, a);
            a = fmaf(xq[tk][3].x, g3.x, a); a = fmaf(xq[tk][3].y, g3.y, a);
            a = fmaf(xq[tk][3].z, g3.z, a); a = fmaf(xq[tk][3].w, g3.w, a);
            acc[tk] = a;
        }
#pragma unroll
        for (int off = 32; off >= 1; off >>= 1) {
            acc[0] += __shfl_xor(acc[0], off, 64);
            acc[1] += __shfl_xor(acc[1], off, 64);
            acc[2] += __shfl_xor(acc[2], off, 64);
            acc[3] += __shfl_xor(acc[3], off, 64);
        }
        if (lane == 0) {
            const float gbe = gb[e];
            logits[wave * 4 + 0][e] = acc[0] + gbe;
            logits[wave * 4 + 1][e] = acc[1] + gbe;
            logits[wave * 4 + 2][e] = acc[2] + gbe;
            logits[wave * 4 + 3][e] = acc[3] + gbe;
        }
    }
    __syncthreads();

    // per-token softmax + top2 (lanes 0..3, one token each; hidden under the
    // W stream). Packed as float4 for a single dependent load in K2.
    if (lane < 4) {
        const int tok = tbase + lane;
        const float* L = logits[wave * 4 + lane];

        float m = L[0];
#pragma unroll
        for (int e = 1; e < NE; ++e) m = fmaxf(m, L[e]);
        float denom = 0.f;
#pragma unroll
        for (int e = 0; e < NE; ++e) denom += expf(L[e] - m);

        int e0 = 0; float l0 = L[0];
#pragma unroll
        for (int e = 1; e < NE; ++e)
            if (L[e] > l0) { l0 = L[e]; e0 = e; }
        int e1 = -1; float l1 = -INFINITY;
#pragma unroll
        for (int e = 0; e < NE; ++e)
            if (e != e0 && L[e] > l1) { l1 = L[e]; e1 = e; }

        const float inv = 1.0f / denom;
        float4 ti;
        ti.x = expf(l0 - m) * inv;
        ti.y = expf(l1 - m) * inv;
        ti.z = __int_as_float(e0);
        ti.w = __int_as_float(e1);
        topinfo[tok] = ti;
    }
}

// ---------------------------------------------------------------------------
// Kernel 2: combine.  One token per wave, 4 waves/block, 2048 blocks.
// x loads issued first (independent), single packed topinfo load, then the
// topinfo-dependent wsum/bias row loads (L2-resident, 256 KB hot set).
// ---------------------------------------------------------------------------
__global__ __launch_bounds__(256) void combine_kernel(
    const float* __restrict__ x,
    const float* __restrict__ wsum,
    const float* __restrict__ bias,
    const float4* __restrict__ topinfo,
    float* __restrict__ out)
{
    const int wave = threadIdx.x >> 6;
    const int lane = threadIdx.x & 63;
    const int tok  = blockIdx.x * 4 + wave;

    // independent loads first: x row + packed gate info
    const float4* x4 = (const float4*)(x + (size_t)tok * DIM);
    float4 xv[4];
#pragma unroll
    for (int j = 0; j < 4; ++j) xv[j] = x4[lane + 64 * j];

    const float4 ti = topinfo[tok];
    const float v0 = ti.x, v1 = ti.y;
    const int   e0 = __float_as_int(ti.z);
    const int   e1 = __float_as_int(ti.w);

    const float4* w0 = (const float4*)(wsum + (size_t)e0 * DIM);
    const float4* w1 = (const float4*)(wsum + (size_t)e1 * DIM);
    const float4* b0 = (const float4*)(bias + (size_t)e0 * DIM);
    const float4* b1 = (const float4*)(bias + (size_t)e1 * DIM);
    float4*       o4 = (float4*)(out + (size_t)tok * DIM);

#pragma unroll
    for (int j = 0; j < 4; ++j) {
        const int idx = lane + 64 * j;
        const float4 a0 = w0[idx], a1 = w1[idx];
        const float4 c0 = b0[idx], c1 = b1[idx];
        float4 o;
        o.x = fmaf(v0, fmaf(xv[j].x, a0.x, c0.x), v1 * fmaf(xv[j].x, a1.x, c1.x));
        o.y = fmaf(v0, fmaf(xv[j].y, a0.y, c0.y), v1 * fmaf(xv[j].y, a1.y, c1.y));
        o.z = fmaf(v0, fmaf(xv[j].z, a0.z, c0.z), v1 * fmaf(xv[j].z, a1.z, c1.z));
        o.w = fmaf(v0, fmaf(xv[j].w, a0.w, c0.w), v1 * fmaf(xv[j].w, a1.w, c1.w));
        o4[idx] = o;
    }
}

// ---------------------------------------------------------------------------
extern "C" void kernel_launch(void* const* d_in, const int* in_sizes, int n_in,
                              void* d_out, int out_size, void* d_ws, size_t ws_size,
                              hipStream_t stream) {
    const float* x    = (const float*)d_in[0];   // [B, I]
    const float* W    = (const float*)d_in[1];   // [E, I, O]
    const float* bias = (const float*)d_in[2];   // [E, O]
    const float* gw   = (const float*)d_in[3];   // [E, I]
    const float* gb   = (const float*)d_in[4];   // [E]
    // d_in[5] = topk (always 2, hardcoded)

    float*  wsum    = (float*)d_ws;                        // 128 KiB
    float4* topinfo = (float4*)((char*)d_ws + (size_t)NE * DIM * 4); // 128 KiB
    float*  out     = (float*)d_out;

    stage1_kernel<<<GATE_BLOCKS + WSUM_BLOCKS, 256, 0, stream>>>(
        W, x, gw, gb, wsum, topinfo);

    combine_kernel<<<NB / 4, 256, 0, stream>>>(x, wsum, bias, topinfo, out);
}

// Round 6
// 63.368 us; speedup vs baseline: 1.0380x; 1.0150x over previous
//
#include <hip/hip_runtime.h>
#include <math.h>

#define NE 32            // experts
#define DIM 1024         // input dim == output dim
#define NB 8192          // batch
#define F4ROW 256        // float4 per row of DIM

#define GATE_BLOCKS 512  // 16 tokens/block (4 waves x 4 tokens)
#define WSUM_BLOCKS 1024 // 32 rows/block (4 waves x 8 rows, pipelined)

// horizontal sum of float4, pairwise
__device__ __forceinline__ float hsum4(float4 v) {
    return (v.x + v.y) + (v.z + v.w);
}

// ---------------------------------------------------------------------------
// Kernel 1: fused  (a) gating -> packed top2 per token [blocks 0..GATE_BLOCKS)
//                  (b) wsum[r] = sum_o W[r,o]           [blocks GATE_BLOCKS..)
// wsum waves are software-pipelined: two 8-load register banks (2 rows each);
// while bank B's loads are in flight the wave reduces bank A, so VMEM never
// drains (the r5 counters showed 13% HBM / 33% occupancy = duty-cycle bound).
// ---------------------------------------------------------------------------
__global__ __launch_bounds__(256) void stage1_kernel(
    const float* __restrict__ W,     // [E, I, O]
    const float* __restrict__ x,     // [B, I]
    const float* __restrict__ gw,    // [E, I]
    const float* __restrict__ gb,    // [E]
    float* __restrict__ wsum,        // [E*I]                 ws
    float4* __restrict__ topinfo)    // [B] {v0,v1,e0,e1}     ws
{
    const int wave = threadIdx.x >> 6;
    const int lane = threadIdx.x & 63;

    if (blockIdx.x >= GATE_BLOCKS) {
        // ---- wsum: 8 rows per wave, 4 batches of 2 rows, double-buffered ----
        const int r0 = ((blockIdx.x - GATE_BLOCKS) * 4 + wave) * 8;
        const float4* Wb = (const float4*)W + (size_t)r0 * F4ROW + lane;

        float4 A0, A1, A2, A3, A4, A5, A6, A7;   // bank A: rows +0,+1
        float4 B0, B1, B2, B3, B4, B5, B6, B7;   // bank B: rows +2,+3

#define LOADBANK(P0,P1,P2,P3,P4,P5,P6,P7, OFF)                                 \
        P0 = Wb[(OFF)      ]; P1 = Wb[(OFF) +  64];                            \
        P2 = Wb[(OFF) + 128]; P3 = Wb[(OFF) + 192];                            \
        P4 = Wb[(OFF) + 256]; P5 = Wb[(OFF) + 320];                            \
        P6 = Wb[(OFF) + 384]; P7 = Wb[(OFF) + 448];

#define REDUCE2(R, P0,P1,P2,P3,P4,P5,P6,P7)                                    \
        {                                                                      \
            float s0 = (hsum4(P0) + hsum4(P1)) + (hsum4(P2) + hsum4(P3));      \
            float s1 = (hsum4(P4) + hsum4(P5)) + (hsum4(P6) + hsum4(P7));      \
            _Pragma("unroll")                                                  \
            for (int off = 32; off >= 1; off >>= 1) {                          \
                s0 += __shfl_xor(s0, off, 64);                                 \
                s1 += __shfl_xor(s1, off, 64);                                 \
            }                                                                  \
            if (lane == 0) { wsum[(R)] = s0; wsum[(R) + 1] = s1; }             \
        }

        LOADBANK(A0,A1,A2,A3,A4,A5,A6,A7, 0)       // rows r0+0, r0+1
        LOADBANK(B0,B1,B2,B3,B4,B5,B6,B7, 512)     // rows r0+2, r0+3
        REDUCE2(r0 + 0, A0,A1,A2,A3,A4,A5,A6,A7)   // waits bank A only
        LOADBANK(A0,A1,A2,A3,A4,A5,A6,A7, 1024)    // rows r0+4, r0+5
        REDUCE2(r0 + 2, B0,B1,B2,B3,B4,B5,B6,B7)
        LOADBANK(B0,B1,B2,B3,B4,B5,B6,B7, 1536)    // rows r0+6, r0+7
        REDUCE2(r0 + 4, A0,A1,A2,A3,A4,A5,A6,A7)
        REDUCE2(r0 + 6, B0,B1,B2,B3,B4,B5,B6,B7)
#undef LOADBANK
#undef REDUCE2
        return;
    }

    // ---- gating: 4 tokens per wave, x rows held in registers (measured
    //      round 2: hidden under the W stream) ----
    __shared__ float logits[16][NE];
    const int tbase = blockIdx.x * 16 + wave * 4;

    const float4* x4 = (const float4*)x;
    float4 xq[4][4];
#pragma unroll
    for (int tk = 0; tk < 4; ++tk)
#pragma unroll
        for (int j = 0; j < 4; ++j)
            xq[tk][j] = x4[(size_t)(tbase + tk) * F4ROW + lane + 64 * j];

    const float4* gw4 = (const float4*)gw;
#pragma unroll 4
    for (int e = 0; e < NE; ++e) {
        const float4 g0 = gw4[(size_t)e * F4ROW + lane];
        const float4 g1 = gw4[(size_t)e * F4ROW + lane + 64];
        const float4 g2 = gw4[(size_t)e * F4ROW + lane + 128];
        const float4 g3 = gw4[(size_t)e * F4ROW + lane + 192];

        float acc[4];
#pragma unroll
        for (int tk = 0; tk < 4; ++tk) {
            float a = 0.f;
            a = fmaf(xq[tk][0].x, g0.x, a); a = fmaf(xq[tk][0].y, g0.y, a);
            a = fmaf(xq[tk][0].z, g0.z, a); a = fmaf(xq[tk][0].w, g0.w, a);
            a = fmaf(xq[tk][1].x, g1.x, a); a = fmaf(xq[tk][1].y, g1.y, a);
            a = fmaf(xq[tk][1].z, g1.z, a); a = fmaf(xq[tk][1].w, g1.w, a);
            a = fmaf(xq[tk][2].x, g2.x, a); a = fmaf(xq[tk][2].y, g2.y, a);
            a = fmaf(xq[tk][2].z, g2.z, a); a = fmaf(xq[tk][2].w, g2.w, a);
            a = fmaf(xq[tk][3].x, g3.x, a); a = fmaf(xq[tk][3].y, g3.y, a);
            a = fmaf(xq[tk][3].w, g3.w, a); a = fmaf(xq[tk][3].z, g3.z, a);
            acc[tk] = a;
        }
#pragma unroll
        for (int off = 32; off >= 1; off >>= 1) {
            acc[0] += __shfl_xor(acc[0], off, 64);
            acc[1] += __shfl_xor(acc[1], off, 64);
            acc[2] += __shfl_xor(acc[2], off, 64);
            acc[3] += __shfl_xor(acc[3], off, 64);
        }
        if (lane == 0) {
            const float gbe = gb[e];
            logits[wave * 4 + 0][e] = acc[0] + gbe;
            logits[wave * 4 + 1][e] = acc[1] + gbe;
            logits[wave * 4 + 2][e] = acc[2] + gbe;
            logits[wave * 4 + 3][e] = acc[3] + gbe;
        }
    }
    __syncthreads();

    // per-token softmax + top2 (lanes 0..3, one token each), packed float4
    if (lane < 4) {
        const int tok = tbase + lane;
        const float* L = logits[wave * 4 + lane];

        float m = L[0];
#pragma unroll
        for (int e = 1; e < NE; ++e) m = fmaxf(m, L[e]);
        float denom = 0.f;
#pragma unroll
        for (int e = 0; e < NE; ++e) denom += expf(L[e] - m);

        int e0 = 0; float l0 = L[0];
#pragma unroll
        for (int e = 1; e < NE; ++e)
            if (L[e] > l0) { l0 = L[e]; e0 = e; }
        int e1 = -1; float l1 = -INFINITY;
#pragma unroll
        for (int e = 0; e < NE; ++e)
            if (e != e0 && L[e] > l1) { l1 = L[e]; e1 = e; }

        const float inv = 1.0f / denom;
        float4 ti;
        ti.x = expf(l0 - m) * inv;
        ti.y = expf(l1 - m) * inv;
        ti.z = __int_as_float(e0);
        ti.w = __int_as_float(e1);
        topinfo[tok] = ti;
    }
}

// ---------------------------------------------------------------------------
// Kernel 2: combine.  One token per wave, 4 waves/block, 2048 blocks.
// Independent x loads issued first; single packed topinfo load; then the
// dependent wsum/bias row loads (256 KB hot set, L2-resident).
// ---------------------------------------------------------------------------
__global__ __launch_bounds__(256) void combine_kernel(
    const float* __restrict__ x,
    const float* __restrict__ wsum,
    const float* __restrict__ bias,
    const float4* __restrict__ topinfo,
    float* __restrict__ out)
{
    const int wave = threadIdx.x >> 6;
    const int lane = threadIdx.x & 63;
    const int tok  = blockIdx.x * 4 + wave;

    const float4* x4 = (const float4*)(x + (size_t)tok * DIM);
    float4 xv[4];
#pragma unroll
    for (int j = 0; j < 4; ++j) xv[j] = x4[lane + 64 * j];

    const float4 ti = topinfo[tok];
    const float v0 = ti.x, v1 = ti.y;
    const int   e0 = __float_as_int(ti.z);
    const int   e1 = __float_as_int(ti.w);

    const float4* w0 = (const float4*)(wsum + (size_t)e0 * DIM);
    const float4* w1 = (const float4*)(wsum + (size_t)e1 * DIM);
    const float4* b0 = (const float4*)(bias + (size_t)e0 * DIM);
    const float4* b1 = (const float4*)(bias + (size_t)e1 * DIM);
    float4*       o4 = (float4*)(out + (size_t)tok * DIM);

#pragma unroll
    for (int j = 0; j < 4; ++j) {
        const int idx = lane + 64 * j;
        const float4 a0 = w0[idx], a1 = w1[idx];
        const float4 c0 = b0[idx], c1 = b1[idx];
        float4 o;
        o.x = fmaf(v0, fmaf(xv[j].x, a0.x, c0.x), v1 * fmaf(xv[j].x, a1.x, c1.x));
        o.y = fmaf(v0, fmaf(xv[j].y, a0.y, c0.y), v1 * fmaf(xv[j].y, a1.y, c1.y));
        o.z = fmaf(v0, fmaf(xv[j].z, a0.z, c0.z), v1 * fmaf(xv[j].z, a1.z, c1.z));
        o.w = fmaf(v0, fmaf(xv[j].w, a0.w, c0.w), v1 * fmaf(xv[j].w, a1.w, c1.w));
        o4[idx] = o;
    }
}

// ---------------------------------------------------------------------------
extern "C" void kernel_launch(void* const* d_in, const int* in_sizes, int n_in,
                              void* d_out, int out_size, void* d_ws, size_t ws_size,
                              hipStream_t stream) {
    const float* x    = (const float*)d_in[0];   // [B, I]
    const float* W    = (const float*)d_in[1];   // [E, I, O]
    const float* bias = (const float*)d_in[2];   // [E, O]
    const float* gw   = (const float*)d_in[3];   // [E, I]
    const float* gb   = (const float*)d_in[4];   // [E]
    // d_in[5] = topk (always 2, hardcoded)

    float*  wsum    = (float*)d_ws;                                   // 128 KiB
    float4* topinfo = (float4*)((char*)d_ws + (size_t)NE * DIM * 4);  // 128 KiB
    float*  out     = (float*)d_out;

    stage1_kernel<<<GATE_BLOCKS + WSUM_BLOCKS, 256, 0, stream>>>(
        W, x, gw, gb, wsum, topinfo);

    combine_kernel<<<NB / 4, 256, 0, stream>>>(x, wsum, bias, topinfo, out);
}

// Round 7
// 58.020 us; speedup vs baseline: 1.1337x; 1.0922x over previous
//
#include <hip/hip_runtime.h>
#include <math.h>

#define NE 32            // experts
#define DIM 1024         // input dim == output dim
#define NB 8192          // batch
#define F4ROW 256        // float4 per row of DIM

#define GATE_BLOCKS 512  // 16 tokens/block (4 waves x 4 tokens)
#define WSUM_BLOCKS 8192 // 4 rows/block (1 row per wave)  — r2 measured-best

// ---------------------------------------------------------------------------
// Kernel 1: fused  (a) gating -> packed top2 per token [blocks 0..GATE_BLOCKS)
//                  (b) wsum[r] = sum_o W[r,o]           [blocks GATE_BLOCKS..)
// wsum: tiny waves (1 row, 4 loads, butterfly, exit) at 8704-block grid ->
// full occupancy / max TLP (r2 measured-best; r5/r6 fat waves regressed).
// gating: gw staged in LDS per block (8 tiles x 4 experts x 16KB), cutting
// gw L2/L3 traffic 4x (256 MB -> 64 MB) — the largest cache-traffic item.
// ---------------------------------------------------------------------------
__global__ __launch_bounds__(256) void stage1_kernel(
    const float* __restrict__ W,     // [E, I, O]
    const float* __restrict__ x,     // [B, I]
    const float* __restrict__ gw,    // [E, I]
    const float* __restrict__ gb,    // [E]
    float* __restrict__ wsum,        // [E*I]                 ws
    float4* __restrict__ topinfo)    // [B] {v0,v1,e0,e1}     ws
{
    // LDS is allocated for every block of this kernel: keep it <= ~18KB so
    // wsum blocks still reach 8 blocks/CU (32 waves).
    __shared__ float gws[4 * DIM];          // one 4-expert tile of gw (16 KB)
    __shared__ float logits[16][NE];        // 2 KB

    const int wave = threadIdx.x >> 6;
    const int lane = threadIdx.x & 63;

    if (blockIdx.x >= GATE_BLOCKS) {
        // ---- wsum: one row per wave (r2 shape) ----
        const int r = (blockIdx.x - GATE_BLOCKS) * 4 + wave;
        const float4* row = (const float4*)(W + (size_t)r * DIM);
        const float4 a = row[lane], b = row[lane + 64],
                     c = row[lane + 128], d = row[lane + 192];
        float s = (((a.x + a.y) + (a.z + a.w)) + ((b.x + b.y) + (b.z + b.w))) +
                  (((c.x + c.y) + (c.z + c.w)) + ((d.x + d.y) + (d.z + d.w)));
#pragma unroll
        for (int off = 32; off >= 1; off >>= 1) s += __shfl_xor(s, off, 64);
        if (lane == 0) wsum[r] = s;
        return;
    }

    // ---- gating: 4 tokens per wave, x rows in registers, gw via LDS tiles --
    const int tbase = blockIdx.x * 16 + wave * 4;

    const float4* x4 = (const float4*)x;
    float4 xq[4][4];
#pragma unroll
    for (int tk = 0; tk < 4; ++tk)
#pragma unroll
        for (int j = 0; j < 4; ++j)
            xq[tk][j] = x4[(size_t)(tbase + tk) * F4ROW + lane + 64 * j];

    const float4* gw4 = (const float4*)gw;
    float4* gws4 = (float4*)gws;

    for (int tile = 0; tile < 8; ++tile) {      // 4 experts per tile
        __syncthreads();                        // previous tile fully consumed
        // cooperative tile load: 1024 float4, 4 per thread, coalesced
#pragma unroll
        for (int k = 0; k < 4; ++k) {
            const int i = threadIdx.x + 256 * k;
            gws4[i] = gw4[(size_t)tile * 1024 + i];
        }
        __syncthreads();

#pragma unroll
        for (int el = 0; el < 4; ++el) {
            const int e = tile * 4 + el;
            const float4 g0 = gws4[el * F4ROW + lane];
            const float4 g1 = gws4[el * F4ROW + lane + 64];
            const float4 g2 = gws4[el * F4ROW + lane + 128];
            const float4 g3 = gws4[el * F4ROW + lane + 192];

            float acc[4];
#pragma unroll
            for (int tk = 0; tk < 4; ++tk) {
                float v = 0.f;
                v = fmaf(xq[tk][0].x, g0.x, v); v = fmaf(xq[tk][0].y, g0.y, v);
                v = fmaf(xq[tk][0].z, g0.z, v); v = fmaf(xq[tk][0].w, g0.w, v);
                v = fmaf(xq[tk][1].x, g1.x, v); v = fmaf(xq[tk][1].y, g1.y, v);
                v = fmaf(xq[tk][1].z, g1.z, v); v = fmaf(xq[tk][1].w, g1.w, v);
                v = fmaf(xq[tk][2].x, g2.x, v); v = fmaf(xq[tk][2].y, g2.y, v);
                v = fmaf(xq[tk][2].z, g2.z, v); v = fmaf(xq[tk][2].w, g2.w, v);
                v = fmaf(xq[tk][3].x, g3.x, v); v = fmaf(xq[tk][3].y, g3.y, v);
                v = fmaf(xq[tk][3].z, g3.z, v); v = fmaf(xq[tk][3].w, g3.w, v);
                acc[tk] = v;
            }
#pragma unroll
            for (int off = 32; off >= 1; off >>= 1) {
                acc[0] += __shfl_xor(acc[0], off, 64);
                acc[1] += __shfl_xor(acc[1], off, 64);
                acc[2] += __shfl_xor(acc[2], off, 64);
                acc[3] += __shfl_xor(acc[3], off, 64);
            }
            if (lane == 0) {
                const float gbe = gb[e];
                logits[wave * 4 + 0][e] = acc[0] + gbe;
                logits[wave * 4 + 1][e] = acc[1] + gbe;
                logits[wave * 4 + 2][e] = acc[2] + gbe;
                logits[wave * 4 + 3][e] = acc[3] + gbe;
            }
        }
    }
    __syncthreads();

    // per-token softmax + top2 (lanes 0..3, one token each), packed float4
    if (lane < 4) {
        const int tok = tbase + lane;
        const float* L = logits[wave * 4 + lane];

        float m = L[0];
#pragma unroll
        for (int e = 1; e < NE; ++e) m = fmaxf(m, L[e]);
        float denom = 0.f;
#pragma unroll
        for (int e = 0; e < NE; ++e) denom += expf(L[e] - m);

        int e0 = 0; float l0 = L[0];
#pragma unroll
        for (int e = 1; e < NE; ++e)
            if (L[e] > l0) { l0 = L[e]; e0 = e; }
        int e1 = -1; float l1 = -INFINITY;
#pragma unroll
        for (int e = 0; e < NE; ++e)
            if (e != e0 && L[e] > l1) { l1 = L[e]; e1 = e; }

        const float inv = 1.0f / denom;
        float4 ti;
        ti.x = expf(l0 - m) * inv;
        ti.y = expf(l1 - m) * inv;
        ti.z = __int_as_float(e0);
        ti.w = __int_as_float(e1);
        topinfo[tok] = ti;
    }
}

// ---------------------------------------------------------------------------
// Kernel 2: combine.  One token per wave, 4 waves/block, 2048 blocks.
// Independent x loads first; single packed topinfo load; then the dependent
// wsum/bias row loads (256 KB hot set, L2-resident).
// ---------------------------------------------------------------------------
__global__ __launch_bounds__(256) void combine_kernel(
    const float* __restrict__ x,
    const float* __restrict__ wsum,
    const float* __restrict__ bias,
    const float4* __restrict__ topinfo,
    float* __restrict__ out)
{
    const int wave = threadIdx.x >> 6;
    const int lane = threadIdx.x & 63;
    const int tok  = blockIdx.x * 4 + wave;

    const float4* x4 = (const float4*)(x + (size_t)tok * DIM);
    float4 xv[4];
#pragma unroll
    for (int j = 0; j < 4; ++j) xv[j] = x4[lane + 64 * j];

    const float4 ti = topinfo[tok];
    const float v0 = ti.x, v1 = ti.y;
    const int   e0 = __float_as_int(ti.z);
    const int   e1 = __float_as_int(ti.w);

    const float4* w0 = (const float4*)(wsum + (size_t)e0 * DIM);
    const float4* w1 = (const float4*)(wsum + (size_t)e1 * DIM);
    const float4* b0 = (const float4*)(bias + (size_t)e0 * DIM);
    const float4* b1 = (const float4*)(bias + (size_t)e1 * DIM);
    float4*       o4 = (float4*)(out + (size_t)tok * DIM);

#pragma unroll
    for (int j = 0; j < 4; ++j) {
        const int idx = lane + 64 * j;
        const float4 a0 = w0[idx], a1 = w1[idx];
        const float4 c0 = b0[idx], c1 = b1[idx];
        float4 o;
        o.x = fmaf(v0, fmaf(xv[j].x, a0.x, c0.x), v1 * fmaf(xv[j].x, a1.x, c1.x));
        o.y = fmaf(v0, fmaf(xv[j].y, a0.y, c0.y), v1 * fmaf(xv[j].y, a1.y, c1.y));
        o.z = fmaf(v0, fmaf(xv[j].z, a0.z, c0.z), v1 * fmaf(xv[j].z, a1.z, c1.z));
        o.w = fmaf(v0, fmaf(xv[j].w, a0.w, c0.w), v1 * fmaf(xv[j].w, a1.w, c1.w));
        o4[idx] = o;
    }
}

// ---------------------------------------------------------------------------
extern "C" void kernel_launch(void* const* d_in, const int* in_sizes, int n_in,
                              void* d_out, int out_size, void* d_ws, size_t ws_size,
                              hipStream_t stream) {
    const float* x    = (const float*)d_in[0];   // [B, I]
    const float* W    = (const float*)d_in[1];   // [E, I, O]
    const float* bias = (const float*)d_in[2];   // [E, O]
    const float* gw   = (const float*)d_in[3];   // [E, I]
    const float* gb   = (const float*)d_in[4];   // [E]
    // d_in[5] = topk (always 2, hardcoded)

    float*  wsum    = (float*)d_ws;                                   // 128 KiB
    float4* topinfo = (float4*)((char*)d_ws + (size_t)NE * DIM * 4);  // 128 KiB
    float*  out     = (float*)d_out;

    stage1_kernel<<<GATE_BLOCKS + WSUM_BLOCKS, 256, 0, stream>>>(
        W, x, gw, gb, wsum, topinfo);

    combine_kernel<<<NB / 4, 256, 0, stream>>>(x, wsum, bias, topinfo, out);
}